// Round 12
// baseline (4272.891 us; speedup 1.0000x reference)
//
#include <hip/hip_runtime.h>
#include <hip/hip_bf16.h>

typedef __attribute__((ext_vector_type(8))) short short8;
typedef __attribute__((ext_vector_type(4))) float f32x4;

__device__ __forceinline__ float gelu_f(float x) {
  return 0.5f * x * (1.0f + erff(x * 0.70710678118654752440f));
}
__device__ __forceinline__ short f2bf(float f) {
  unsigned u = __float_as_uint(f);
  u += 0x7fffu + ((u >> 16) & 1u);
  return (short)(u >> 16);
}
__device__ __forceinline__ float bf2f(short s) {
  return __uint_as_float(((unsigned)(unsigned short)s) << 16);
}
// hi/lo bf16 split: v = hi + lo + O(2^-18 v)
__device__ __forceinline__ void split2(float v, short& h, short& l) {
  h = f2bf(v);
  l = f2bf(v - bf2f(h));
}
// swizzle a column index within its 64-elem group by row (involution)
__device__ __forceinline__ int swz(int col, int row) {
  return (col & ~63) | ((col & 63) ^ ((row & 7) << 3));
}

__device__ __forceinline__ float block_sum_256(float v, float* sb) {
#pragma unroll
  for (int o = 1; o < 64; o <<= 1) v += __shfl_xor(v, o, 64);
  if ((threadIdx.x & 63) == 0) sb[threadIdx.x >> 6] = v;
  __syncthreads();
  float r = sb[0] + sb[1] + sb[2] + sb[3];
  __syncthreads();
  return r;
}

// ---------------- prep kernel: embed+LN1 and all weight converts ----------
// NOTE: prep moves 1.36 GB logical in ~236 us = 5.8 TB/s ~= BW roofline.
struct PrepArgs {
  const float *x, *cw, *cb, *cls, *pos, *ln1g, *ln1b;
  float* tok;
  short *zh, *zl;
  const float *Wqkv, *Wo, *Wm1, *Wm2;
  short *Wqh, *Wql, *Woh, *Wol, *W1h, *W1l, *W2h, *W2l;
};

// weight transpose+convert v3: fp32 [K][N] -> bf16 hi/lo [N][K] swizzled.
// Block = 128 n x 64 k (FULL swizzle group -> full-cacheline writes, no RFO).
__device__ void conv_body(const float* __restrict__ in,
                          short* __restrict__ outh, short* __restrict__ outl,
                          int K, int ldn, int group, long long gstride, int bx,
                          int by, float* tile /* 4*2113 floats */) {
  const int n0 = bx * 128;
  const int k0 = by * 64;
  const int tid = threadIdx.x;
  // read phase: lane -> n-quad j=tid&31, k-rows kb*8..kb*8+7 (kb=tid>>5)
  {
    const int j = tid & 31;
    const int kb = tid >> 5;  // 0..7
    const int n = n0 + 4 * j;
    const long long nbase = (long long)(n / group) * gstride + (n % group);
#pragma unroll
    for (int i = 0; i < 8; ++i) {
      const int k = kb * 8 + i;
      float4 v4 = *(const float4*)(in + nbase + (long long)(k0 + k) * ldn);
      tile[0 * 2113 + k * 33 + j] = v4.x;
      tile[1 * 2113 + k * 33 + j] = v4.y;
      tile[2 * 2113 + k * 33 + j] = v4.z;
      tile[3 * 2113 + k * 33 + j] = v4.w;
    }
  }
  __syncthreads();
  // write phase: thread (r=tid>>1, hf=tid&1) writes 64B h + 64B l of row n0+r
  {
    const int r = tid >> 1;
    const int hf = tid & 1;
    const int n = n0 + r;
    const int e = r & 3, jj = r >> 2;
    const int g8 = n & 7;
    const float* te = tile + e * 2113 + jj;
    const long long obase = (long long)n * K + k0;
#pragma unroll
    for (int j2 = 0; j2 < 4; ++j2) {
      const int s = hf * 4 + j2;  // dest octet slot within 64-elem group
      const int m = s ^ g8;       // source octet
      short8 sh, sl;
#pragma unroll
      for (int e8 = 0; e8 < 8; ++e8) {
        float v = te[(m * 8 + e8) * 33];
        short h, L;
        split2(v, h, L);
        sh[e8] = h;
        sl[e8] = L;
      }
      *(short8*)(outh + obase + s * 8) = sh;
      *(short8*)(outl + obase + s * 8) = sl;
    }
  }
}

__global__ __launch_bounds__(256) void prep_kernel(PrepArgs p) {
  __shared__ __align__(16) float smem[4 * 2113];  // 33.8 KB
  const int t = blockIdx.x;
  if (t < 520) {
    float* sb = smem;
    // patch embed + pos emb + LN1(layer0)
    int r = t;  // b*65+s
    int b = r / 65, s = r % 65;
    int d = threadIdx.x;
    float val;
    if (s == 0) {
      val = p.cls[d];
    } else {
      int pp = s - 1, pi = pp >> 3, pj = pp & 7;
      const float* xb = p.x + b * 3072 + pi * 4 * 32 + pj * 4;
      const float* w = p.cw + d * 48;
      float acc = p.cb[d];
#pragma unroll
      for (int c = 0; c < 3; ++c)
#pragma unroll
        for (int i = 0; i < 4; ++i)
#pragma unroll
          for (int j = 0; j < 4; ++j)
            acc += xb[c * 1024 + i * 32 + j] * w[c * 16 + i * 4 + j];
      val = acc;
    }
    val += p.pos[s * 256 + d];
    p.tok[r * 256 + d] = val;
    float mean = block_sum_256(val, sb) * (1.0f / 256.0f);
    float dv = val - mean;
    float var = block_sum_256(dv * dv, sb) * (1.0f / 256.0f);
    float z = dv * rsqrtf(var + 1e-5f) * p.ln1g[d] + p.ln1b[d];
    short h, L;
    split2(z, h, L);
    p.zh[r * 256 + swz(d, r)] = h;
    p.zl[r * 256 + swz(d, r)] = L;
    return;
  }
  const int u = t - 520;
  const int layer = u / 576;
  const int r = u % 576;
  if (r < 384) {
    // Wqkv: K=256 (4 k-blk), N=12288 (96 n-blk), ldn=768, head-grouped
    conv_body(p.Wqkv + (long long)layer * 3145728,
              p.Wqh + (long long)layer * 3145728,
              p.Wql + (long long)layer * 3145728, 256, 768, 768, 196608LL,
              r % 96, r / 96, smem);
  } else if (r < 512) {
    int v = r - 384;  // Wo: K=4096 (64 k-blk), N=256 (2 n-blk)
    conv_body(p.Wo + (long long)layer * 1048576,
              p.Woh + (long long)layer * 1048576,
              p.Wol + (long long)layer * 1048576, 4096, 256, 1 << 30, 0LL,
              v % 2, v / 2, smem);
  } else if (r < 544) {
    int v = r - 512;  // Wm1: K=256 (4 k-blk), N=1024 (8 n-blk)
    conv_body(p.Wm1 + (long long)layer * 262144,
              p.W1h + (long long)layer * 262144,
              p.W1l + (long long)layer * 262144, 256, 1024, 1 << 30, 0LL,
              v % 8, v / 8, smem);
  } else {
    int v = r - 544;  // Wm2: K=1024 (16 k-blk), N=256 (2 n-blk)
    conv_body(p.Wm2 + (long long)layer * 262144,
              p.W2h + (long long)layer * 262144,
              p.W2l + (long long)layer * 262144, 1024, 256, 1 << 30, 0LL,
              v % 2, v / 2, smem);
  }
}

// -------- MFMA bf16x3 GEMM (fp32-quality), 128x128 tile, m97 structure ----
// MODE 0: C=A@B+bias -> fp32 out32          (no erf in this instantiation)
// MODE 1: C=gelu(A@B+bias) -> bf16 hi/lo swizzled rows (MLP1 only)
// MODE 2: fp32 partials -> P[blockIdx.z]    (split-K; no erf)
// Separate instantiations => register allocation is NOT contaminated by the
// erff expansion in MODE 1 (round-11 lesson: one shared body slowed QKV).
template <int MODE>
__global__ __launch_bounds__(256) void gemm_x3(
    const short* __restrict__ Ah, const short* __restrict__ Al,
    const short* __restrict__ Bh, const short* __restrict__ Bl, int M, int N,
    int K, int kchunk, const float* __restrict__ bias,
    float* __restrict__ out32, short* __restrict__ o16h,
    short* __restrict__ o16l, float* __restrict__ P) {
  __shared__ short Ash[128 * 64];
  __shared__ short Asl[128 * 64];
  __shared__ short Bsh[128 * 64];
  __shared__ short Bsl[128 * 64];
  const int tid = threadIdx.x;
  const int w = tid >> 6, l = tid & 63;
  const int col0 = blockIdx.x * 128;
  const int row0 = blockIdx.y * 128;
  const int kbeg = blockIdx.z * kchunk;
  const int kend = kbeg + kchunk;
  const int wm = w >> 1, wn = w & 1;  // 2x2 waves of 64x64

  f32x4 acc[4][4];
#pragma unroll
  for (int i = 0; i < 4; ++i)
#pragma unroll
    for (int j = 0; j < 4; ++j) acc[i][j] = (f32x4)(0.f);

  const int srow = l >> 3;  // row within 8-row chunk
  const int sslot = l & 7;  // 16B slot

#define STAGE4(dst, src, rbase)                                            \
  {                                                                        \
    _Pragma("unroll") for (int i = 0; i < 4; ++i) {                        \
      int r = (w * 4 + i) * 8 + srow;                                      \
      const char* gp =                                                     \
          (const char*)(src + (size_t)(rbase + r) * K + k0) + sslot * 16;  \
      short* lp = dst + (w * 4 + i) * 512;                                 \
      __builtin_amdgcn_global_load_lds(                                    \
          (const __attribute__((address_space(1))) unsigned int*)gp,       \
          (__attribute__((address_space(3))) unsigned int*)lp, 16, 0, 0);  \
    }                                                                      \
  }

  for (int k0 = kbeg; k0 < kend; k0 += 64) {
    __syncthreads();
    STAGE4(Ash, Ah, row0)
    STAGE4(Asl, Al, row0)
    STAGE4(Bsh, Bh, col0)
    STAGE4(Bsl, Bl, col0)
    __syncthreads();
#pragma unroll
    for (int kc = 0; kc < 2; ++kc) {
      short8 ah[4], al[4], bh[4], bl[4];
#pragma unroll
      for (int mi = 0; mi < 4; ++mi) {
        int row = wm * 64 + mi * 16 + (l & 15);
        int slot = (kc * 4 + (l >> 4)) ^ (row & 7);
        ah[mi] = *(const short8*)&Ash[row * 64 + slot * 8];
        al[mi] = *(const short8*)&Asl[row * 64 + slot * 8];
      }
#pragma unroll
      for (int ni = 0; ni < 4; ++ni) {
        int row = wn * 64 + ni * 16 + (l & 15);
        int slot = (kc * 4 + (l >> 4)) ^ (row & 7);
        bh[ni] = *(const short8*)&Bsh[row * 64 + slot * 8];
        bl[ni] = *(const short8*)&Bsl[row * 64 + slot * 8];
      }
#pragma unroll
      for (int mi = 0; mi < 4; ++mi)
#pragma unroll
        for (int ni = 0; ni < 4; ++ni) {
          acc[mi][ni] = __builtin_amdgcn_mfma_f32_16x16x32_bf16(
              ah[mi], bh[ni], acc[mi][ni], 0, 0, 0);
          acc[mi][ni] = __builtin_amdgcn_mfma_f32_16x16x32_bf16(
              ah[mi], bl[ni], acc[mi][ni], 0, 0, 0);
          acc[mi][ni] = __builtin_amdgcn_mfma_f32_16x16x32_bf16(
              al[mi], bh[ni], acc[mi][ni], 0, 0, 0);
        }
    }
  }
#undef STAGE4

#pragma unroll
  for (int mi = 0; mi < 4; ++mi) {
#pragma unroll
    for (int ni = 0; ni < 4; ++ni) {
      int row = row0 + wm * 64 + mi * 16 + (l >> 4) * 4;
      int col = col0 + wn * 64 + ni * 16 + (l & 15);
      if constexpr (MODE == 0) {
        float bc = bias ? bias[col] : 0.f;
#pragma unroll
        for (int r = 0; r < 4; ++r)
          if (row + r < M)
            out32[(size_t)(row + r) * N + col] = acc[mi][ni][r] + bc;
      } else if constexpr (MODE == 1) {
        float bc = bias ? bias[col] : 0.f;
#pragma unroll
        for (int r = 0; r < 4; ++r)
          if (row + r < M) {
            float v = gelu_f(acc[mi][ni][r] + bc);
            short h, L;
            split2(v, h, L);
            o16h[(size_t)(row + r) * N + swz(col, row + r)] = h;
            o16l[(size_t)(row + r) * N + swz(col, row + r)] = L;
          }
      } else {
        float* Pz = P + (size_t)blockIdx.z * M * N;
#pragma unroll
        for (int r = 0; r < 4; ++r)
          if (row + r < M) Pz[(size_t)(row + r) * N + col] = acc[mi][ni][r];
      }
    }
  }
}

// ------ split-K reduce + bias + act + residual (+ LN); NSPLIT unrolled ----
template <int NSPLIT>
__global__ __launch_bounds__(256) void epilogue_kernel(
    const float* __restrict__ P, int M, int N, const float* __restrict__ bias,
    const float* __restrict__ res, float* __restrict__ out32,
    short* __restrict__ o16h, short* __restrict__ o16l, int act,
    const float* __restrict__ g, const float* __restrict__ bln,
    short* __restrict__ z16h, short* __restrict__ z16l) {
  __shared__ float sb[4];
  int r = blockIdx.x;
  float myval = 0.f;
  for (int c = threadIdx.x; c < N; c += 256) {
    const float* pp = P + (long long)r * N + c;
    float acc = 0.f;
#pragma unroll
    for (int s = 0; s < NSPLIT; ++s) acc += pp[(long long)s * M * N];
    acc += bias[c];
    if (act) acc = gelu_f(acc);
    if (res) acc += res[(long long)r * N + c];
    if (out32) out32[(long long)r * N + c] = acc;
    if (o16h) {
      short h, L;
      split2(acc, h, L);
      o16h[(long long)r * N + swz(c, r)] = h;
      o16l[(long long)r * N + swz(c, r)] = L;
    }
    myval = acc;
  }
  if (z16h) {  // N==256 only
    float mean = block_sum_256(myval, sb) * (1.f / 256.f);
    float dv = myval - mean;
    float var = block_sum_256(dv * dv, sb) * (1.f / 256.f);
    float z = dv * rsqrtf(var + 1e-5f) * g[threadIdx.x] + bln[threadIdx.x];
    short h, L;
    split2(z, h, L);
    z16h[r * 256 + swz((int)threadIdx.x, r)] = h;
    z16l[r * 256 + swz((int)threadIdx.x, r)] = L;
  }
}

// ------- attention (fp32 qkv in, hi/lo bf16 out), 17 q-rows per block -----
#define AROWS 17
__global__ __launch_bounds__(256) void attn_kernel(const float* __restrict__ qkv,
                                                   short* __restrict__ Oh,
                                                   short* __restrict__ Ol) {
  __shared__ float qs[AROWS + 1][256];
  __shared__ float Ks[68][68];
  __shared__ float ps[AROWS][66];
  const int tid = threadIdx.x;
  const int s0 = blockIdx.x * AROWS;
  const int bh = blockIdx.y;
  const int b = bh >> 4, h = bh & 15;
  const long long base = (long long)(b * 65) * 12288 + h * 768;

#pragma unroll
  for (int i = 0; i < AROWS; ++i) {
    int s = s0 + i;
    qs[i][tid] = (s < 65) ? qkv[base + (long long)s * 12288 + tid] : 0.f;
  }

  const int up = tid / 17, tg = tid % 17;
  const int i0 = up * 2, t0 = tg * 4;
  const bool uval = (tid < 153);
  float acc[2][4] = {};
  for (int dc = 0; dc < 256; dc += 64) {
    __syncthreads();
    for (int idx = tid; idx < 65 * 64; idx += 256) {
      int t = idx >> 6, dd = idx & 63;
      Ks[t][dd] = qkv[base + (long long)t * 12288 + 256 + dc + dd];
    }
    __syncthreads();
    if (uval) {
#pragma unroll
      for (int d4 = 0; d4 < 64; d4 += 4) {
        float4 qa = *(const float4*)&qs[i0][dc + d4];
        float4 qb = *(const float4*)&qs[i0 + 1][dc + d4];
#pragma unroll
        for (int c = 0; c < 4; ++c) {
          float4 kv = *(const float4*)&Ks[t0 + c][d4];
          acc[0][c] += qa.x * kv.x + qa.y * kv.y + qa.z * kv.z + qa.w * kv.w;
          acc[1][c] += qb.x * kv.x + qb.y * kv.y + qb.z * kv.z + qb.w * kv.w;
        }
      }
    }
  }
  if (uval) {
#pragma unroll
    for (int ii = 0; ii < 2; ++ii) {
      int i = i0 + ii;
      if (i < AROWS && (s0 + i) < 65) {
#pragma unroll
        for (int c = 0; c < 4; ++c) {
          int t = t0 + c;
          if (t < 65) ps[i][t] = acc[ii][c] * 0.25f;
        }
      }
    }
  }
  __syncthreads();

  if (tid < AROWS && (s0 + tid) < 65) {
    float* row = ps[tid];
    float m = row[0];
    for (int t = 1; t < 65; ++t) m = fmaxf(m, row[t]);
    float sum = 0.f;
    for (int t = 0; t < 65; ++t) {
      float e = expf(row[t] - m);
      row[t] = e;
      sum += e;
    }
    float inv = 1.f / sum;
    for (int t = 0; t < 65; ++t) row[t] *= inv;
  }
  __syncthreads();

  float oacc[AROWS];
#pragma unroll
  for (int i = 0; i < AROWS; ++i) oacc[i] = 0.f;
  const float* vp = qkv + base + 512 + tid;
  for (int t = 0; t < 65; ++t) {
    float vtd = vp[(long long)t * 12288];
#pragma unroll
    for (int i = 0; i < AROWS; ++i) oacc[i] += ps[i][t] * vtd;
  }
#pragma unroll
  for (int i = 0; i < AROWS; ++i) {
    int s = s0 + i;
    if (s < 65) {
      int row = b * 65 + s;
      int col = h * 256 + ((tid & ~63) | ((tid & 63) ^ ((row & 7) << 3)));
      short hh, LL;
      split2(oacc[i], hh, LL);
      Oh[(long long)row * 4096 + col] = hh;
      Ol[(long long)row * 4096 + col] = LL;
    }
  }
}

// ---------------- head GEMMs (fp32, tiny) ----------------
template <int KS>
__global__ __launch_bounds__(256) void head_gemm2(
    const float* __restrict__ A, int lda, const float* __restrict__ B,
    const float* __restrict__ bias, float* __restrict__ C, int N, int K,
    int act) {
  constexpr int COLS = 256 / KS;
  __shared__ float red[KS][COLS];
  const int lane = threadIdx.x % COLS;
  const int ks = threadIdx.x / COLS;
  const int c = blockIdx.x * COLS + lane;
  const int r = blockIdx.y;
  const float* a = A + (long long)r * lda;
  float acc = 0.f;
  const int kc = K / KS;
  if (c < N) {
    const float* ap = a + ks * kc;
    const float* bp = B + (long long)(ks * kc) * N + c;
#pragma unroll 8
    for (int k = 0; k < kc; ++k) acc += ap[k] * bp[(long long)k * N];
  }
  red[ks][lane] = acc;
  __syncthreads();
  if (ks == 0 && c < N) {
    float v = bias[c];
#pragma unroll
    for (int s = 0; s < KS; ++s) v += red[s][lane];
    if (act) v = gelu_f(v);
    C[(long long)r * N + c] = v;
  }
}

extern "C" void kernel_launch(void* const* d_in, const int* in_sizes, int n_in,
                              void* d_out, int out_size, void* d_ws,
                              size_t ws_size, hipStream_t stream) {
  const float* x = (const float*)d_in[0];
  const float* conv_w = (const float*)d_in[1];
  const float* conv_b = (const float*)d_in[2];
  const float* cls = (const float*)d_in[3];
  const float* pos = (const float*)d_in[4];
  const float* Wqkv = (const float*)d_in[5];
  const float* bqkv = (const float*)d_in[6];
  const float* Wo = (const float*)d_in[7];
  const float* bo = (const float*)d_in[8];
  const float* ln1g = (const float*)d_in[9];
  const float* ln1b = (const float*)d_in[10];
  const float* ln2g = (const float*)d_in[11];
  const float* ln2b = (const float*)d_in[12];
  const float* Wm1 = (const float*)d_in[13];
  const float* bm1 = (const float*)d_in[14];
  const float* Wm2 = (const float*)d_in[15];
  const float* bm2 = (const float*)d_in[16];
  const float* Wh1 = (const float*)d_in[17];
  const float* bh1 = (const float*)d_in[18];
  const float* Wh2 = (const float*)d_in[19];
  const float* bh2 = (const float*)d_in[20];
  const float* Wh3 = (const float*)d_in[21];
  const float* bh3 = (const float*)d_in[22];
  float* out = (float*)d_out;

  // ---- workspace map (float units; identical to round-5 proven map) ----
  float* ws = (float*)d_ws;
  float* tok = ws;
  float* y1 = ws + 163840;
  float* Pb = ws + 327680;
  float* qkvf = ws + 2457600;
  short* zh = (short*)(ws + 8847360);
  short* zl = (short*)(ws + 8929280);
  short* Oh = (short*)(ws + 9011200);
  short* Ol = (short*)(ws + 10321920);
  short* h1h = (short*)(ws + 11632640);
  short* h1l = (short*)(ws + 11960320);
  float* hh1 = ws + 12288000;
  float* hh2 = ws + 12296192;
  short* Wqh = (short*)(ws + 12298240);
  short* Wql = (short*)(ws + 50046976);
  short* Woh = (short*)(ws + 87795712);
  short* Wol_ = (short*)(ws + 100378624);
  short* W1h = (short*)(ws + 112961536);
  short* W1l = (short*)(ws + 116107264);
  short* W2h = (short*)(ws + 119252992);
  short* W2l = (short*)(ws + 122398720);

  const int M = 520;

  // one prep dispatch: embed+LN1 (520 blocks) + all weight converts
  PrepArgs p;
  p.x = x; p.cw = conv_w; p.cb = conv_b; p.cls = cls; p.pos = pos;
  p.ln1g = ln1g; p.ln1b = ln1b;
  p.tok = tok; p.zh = zh; p.zl = zl;
  p.Wqkv = Wqkv; p.Wo = Wo; p.Wm1 = Wm1; p.Wm2 = Wm2;
  p.Wqh = Wqh; p.Wql = Wql; p.Woh = Woh; p.Wol = Wol_;
  p.W1h = W1h; p.W1l = W1l; p.W2h = W2h; p.W2l = W2l;
  prep_kernel<<<520 + 24 * 576, 256, 0, stream>>>(p);

  for (int l = 0; l < 24; ++l) {
    const short* Wqhl = Wqh + (long long)l * 3145728;
    const short* Wqll = Wql + (long long)l * 3145728;
    const short* Wohl = Woh + (long long)l * 1048576;
    const short* Woll = Wol_ + (long long)l * 1048576;
    const short* W1hl = W1h + (long long)l * 262144;
    const short* W1ll = W1l + (long long)l * 262144;
    const short* W2hl = W2h + (long long)l * 262144;
    const short* W2ll = W2l + (long long)l * 262144;
    const float* bq = bqkv + l * 12288;
    const float* bol = bo + l * 256;
    const float* b1 = bm1 + l * 1024;
    const float* b2 = bm2 + l * 256;

    // QKV: z @ Wq -> qkvf fp32 (+bias)   [MODE 0]
    gemm_x3<0><<<dim3(96, 5, 1), 256, 0, stream>>>(
        zh, zl, Wqhl, Wqll, M, 12288, 256, 256, bq, qkvf, nullptr, nullptr,
        nullptr);

    attn_kernel<<<dim3(4, 128), 256, 0, stream>>>(qkvf, Oh, Ol);

    // Wo: O(520x4096) @ Wo'(256x4096), split-K 16 -> Pb   [MODE 2]
    gemm_x3<2><<<dim3(2, 5, 16), 256, 0, stream>>>(
        Oh, Ol, Wohl, Woll, M, 256, 4096, 256, nullptr, nullptr, nullptr,
        nullptr, Pb);
    epilogue_kernel<16><<<520, 256, 0, stream>>>(
        Pb, M, 256, bol, tok, y1, nullptr, nullptr, 0, ln2g + l * 256,
        ln2b + l * 256, zh, zl);

    // MLP1: z @ Wm1'(1024x256), nsplit=1, FUSED bias+gelu -> h1   [MODE 1]
    gemm_x3<1><<<dim3(8, 5, 1), 256, 0, stream>>>(
        zh, zl, W1hl, W1ll, M, 1024, 256, 256, b1, nullptr, h1h, h1l,
        nullptr);

    // MLP2: h1 @ Wm2'(256x1024), split-K 16 -> Pb   [MODE 2]
    gemm_x3<2><<<dim3(2, 5, 16), 256, 0, stream>>>(
        h1h, h1l, W2hl, W2ll, M, 256, 1024, 64, nullptr, nullptr, nullptr,
        nullptr, Pb);
    const float* ng = (l < 23) ? ln1g + (l + 1) * 256 : nullptr;
    const float* nb = (l < 23) ? ln1b + (l + 1) * 256 : nullptr;
    short* nzh = (l < 23) ? zh : nullptr;
    short* nzl = (l < 23) ? zl : nullptr;
    epilogue_kernel<16><<<520, 256, 0, stream>>>(Pb, M, 256, b2, y1, tok,
                                                 nullptr, nullptr, 1, ng, nb,
                                                 nzh, nzl);
  }

  head_gemm2<4><<<dim3(16, 8), 256, 0, stream>>>(tok, 16640, Wh1, bh1, hh1,
                                                 1024, 256, 1);
  head_gemm2<8><<<dim3(8, 8), 256, 0, stream>>>(hh1, 1024, Wh2, bh2, hh2, 256,
                                                1024, 1);
  head_gemm2<4><<<dim3(16, 8), 256, 0, stream>>>(hh2, 256, Wh3, bh3, out, 1000,
                                                 256, 0);
}

// Round 13
// 3091.131 us; speedup vs baseline: 1.3823x; 1.3823x over previous
//
#include <hip/hip_runtime.h>
#include <hip/hip_bf16.h>

typedef __attribute__((ext_vector_type(8))) short short8;
typedef __attribute__((ext_vector_type(4))) float f32x4;

__device__ __forceinline__ float gelu_f(float x) {
  return 0.5f * x * (1.0f + erff(x * 0.70710678118654752440f));
}
__device__ __forceinline__ short f2bf(float f) {
  unsigned u = __float_as_uint(f);
  u += 0x7fffu + ((u >> 16) & 1u);
  return (short)(u >> 16);
}
__device__ __forceinline__ float bf2f(short s) {
  return __uint_as_float(((unsigned)(unsigned short)s) << 16);
}
// hi/lo bf16 split: v = hi + lo + O(2^-18 v)
__device__ __forceinline__ void split2(float v, short& h, short& l) {
  h = f2bf(v);
  l = f2bf(v - bf2f(h));
}
// swizzle a column index within its 64-elem group by row (involution)
__device__ __forceinline__ int swz(int col, int row) {
  return (col & ~63) | ((col & 63) ^ ((row & 7) << 3));
}

__device__ __forceinline__ float block_sum_256(float v, float* sb) {
#pragma unroll
  for (int o = 1; o < 64; o <<= 1) v += __shfl_xor(v, o, 64);
  if ((threadIdx.x & 63) == 0) sb[threadIdx.x >> 6] = v;
  __syncthreads();
  float r = sb[0] + sb[1] + sb[2] + sb[3];
  __syncthreads();
  return r;
}

// ---------------- prep kernel: embed+LN1 and all weight converts ----------
struct PrepArgs {
  const float *x, *cw, *cb, *cls, *pos, *ln1g, *ln1b;
  float* tok;
  short *zh, *zl;
  const float *Wqkv, *Wo, *Wm1, *Wm2;
  short *Wqh, *Wql, *Woh, *Wol, *W1h, *W1l, *W2h, *W2l;
};

// weight transpose+convert v3: fp32 [K][N] -> bf16 hi/lo [N][K] swizzled.
// Block = 128 n x 64 k (FULL swizzle group -> full-cacheline writes, no RFO).
// LDS: 4 element planes [64][33] (scalar stores, bank-conflict-free).
// Output bytes identical to previous rounds: out[n*K + swz(k,n)].
__device__ void conv_body(const float* __restrict__ in,
                          short* __restrict__ outh, short* __restrict__ outl,
                          int K, int ldn, int group, long long gstride, int bx,
                          int by, float* tile /* 4*64*33 floats */) {
  const int n0 = bx * 128;
  const int k0 = by * 64;
  const int tid = threadIdx.x;
  // read phase: lane -> n-quad j=tid&31, k-rows kb*8..kb*8+7 (kb=tid>>5)
  {
    const int j = tid & 31;
    const int kb = tid >> 5;  // 0..7
    const int n = n0 + 4 * j;
    const long long nbase = (long long)(n / group) * gstride + (n % group);
#pragma unroll
    for (int i = 0; i < 8; ++i) {
      const int k = kb * 8 + i;
      float4 v4 = *(const float4*)(in + nbase + (long long)(k0 + k) * ldn);
      tile[0 * 2112 + k * 33 + j] = v4.x;
      tile[1 * 2112 + k * 33 + j] = v4.y;
      tile[2 * 2112 + k * 33 + j] = v4.z;
      tile[3 * 2112 + k * 33 + j] = v4.w;
    }
  }
  __syncthreads();
  // write phase: thread (r=tid>>1, hf=tid&1) writes 64B h + 64B l of row n0+r
  {
    const int r = tid >> 1;
    const int hf = tid & 1;
    const int n = n0 + r;
    const int e = r & 3, jj = r >> 2;
    const int g8 = n & 7;
    const float* te = tile + e * 2112 + jj;
    const long long obase = (long long)n * K + k0;
#pragma unroll
    for (int j2 = 0; j2 < 4; ++j2) {
      const int s = hf * 4 + j2;  // dest octet slot within 64-elem group
      const int m = s ^ g8;       // source octet
      short8 sh, sl;
#pragma unroll
      for (int e8 = 0; e8 < 8; ++e8) {
        float v = te[(m * 8 + e8) * 33];
        short h, L;
        split2(v, h, L);
        sh[e8] = h;
        sl[e8] = L;
      }
      *(short8*)(outh + obase + s * 8) = sh;
      *(short8*)(outl + obase + s * 8) = sl;
    }
  }
}

__global__ __launch_bounds__(256) void prep_kernel(PrepArgs p) {
  __shared__ __align__(16) float smem[4 * 64 * 33];  // 33.8 KB
  const int t = blockIdx.x;
  if (t < 520) {
    float* sb = smem;
    // patch embed + pos emb + LN1(layer0)
    int r = t;  // b*65+s
    int b = r / 65, s = r % 65;
    int d = threadIdx.x;
    float val;
    if (s == 0) {
      val = p.cls[d];
    } else {
      int pp = s - 1, pi = pp >> 3, pj = pp & 7;
      const float* xb = p.x + b * 3072 + pi * 4 * 32 + pj * 4;
      const float* w = p.cw + d * 48;
      float acc = p.cb[d];
#pragma unroll
      for (int c = 0; c < 3; ++c)
#pragma unroll
        for (int i = 0; i < 4; ++i)
#pragma unroll
          for (int j = 0; j < 4; ++j)
            acc += xb[c * 1024 + i * 32 + j] * w[c * 16 + i * 4 + j];
      val = acc;
    }
    val += p.pos[s * 256 + d];
    p.tok[r * 256 + d] = val;
    float mean = block_sum_256(val, sb) * (1.0f / 256.0f);
    float dv = val - mean;
    float var = block_sum_256(dv * dv, sb) * (1.0f / 256.0f);
    float z = dv * rsqrtf(var + 1e-5f) * p.ln1g[d] + p.ln1b[d];
    short h, L;
    split2(z, h, L);
    p.zh[r * 256 + swz(d, r)] = h;
    p.zl[r * 256 + swz(d, r)] = L;
    return;
  }
  const int u = t - 520;
  const int layer = u / 576;
  const int r = u % 576;
  if (r < 384) {
    // Wqkv: K=256 (4 k-blk), N=12288 (96 n-blk), ldn=768, head-grouped
    conv_body(p.Wqkv + (long long)layer * 3145728,
              p.Wqh + (long long)layer * 3145728,
              p.Wql + (long long)layer * 3145728, 256, 768, 768, 196608LL,
              r % 96, r / 96, smem);
  } else if (r < 512) {
    int v = r - 384;  // Wo: K=4096 (64 k-blk), N=256 (2 n-blk)
    conv_body(p.Wo + (long long)layer * 1048576,
              p.Woh + (long long)layer * 1048576,
              p.Wol + (long long)layer * 1048576, 4096, 256, 1 << 30, 0LL,
              v % 2, v / 2, smem);
  } else if (r < 544) {
    int v = r - 512;  // Wm1: K=256 (4 k-blk), N=1024 (8 n-blk)
    conv_body(p.Wm1 + (long long)layer * 262144,
              p.W1h + (long long)layer * 262144,
              p.W1l + (long long)layer * 262144, 256, 1024, 1 << 30, 0LL,
              v % 8, v / 8, smem);
  } else {
    int v = r - 544;  // Wm2: K=1024 (16 k-blk), N=256 (2 n-blk)
    conv_body(p.Wm2 + (long long)layer * 262144,
              p.W2h + (long long)layer * 262144,
              p.W2l + (long long)layer * 262144, 1024, 256, 1 << 30, 0LL,
              v % 2, v / 2, smem);
  }
}

// -------- MFMA bf16x3 GEMM (fp32-quality), 128x128 tile, m97 structure ----
__global__ __launch_bounds__(256) void gemm_x3(
    const short* __restrict__ Ah, const short* __restrict__ Al,
    const short* __restrict__ Bh, const short* __restrict__ Bl, int M, int N,
    int K, int kchunk, const float* __restrict__ bias,
    float* __restrict__ out32, float* __restrict__ P) {
  __shared__ short Ash[128 * 64];
  __shared__ short Asl[128 * 64];
  __shared__ short Bsh[128 * 64];
  __shared__ short Bsl[128 * 64];
  const int tid = threadIdx.x;
  const int w = tid >> 6, l = tid & 63;
  const int col0 = blockIdx.x * 128;
  const int row0 = blockIdx.y * 128;
  const int kbeg = blockIdx.z * kchunk;
  const int kend = kbeg + kchunk;
  const int wm = w >> 1, wn = w & 1;  // 2x2 waves of 64x64

  f32x4 acc[4][4];
#pragma unroll
  for (int i = 0; i < 4; ++i)
#pragma unroll
    for (int j = 0; j < 4; ++j) acc[i][j] = (f32x4)(0.f);

  const int srow = l >> 3;  // row within 8-row chunk
  const int sslot = l & 7;  // 16B slot

#define STAGE4(dst, src, rbase)                                            \
  {                                                                        \
    _Pragma("unroll") for (int i = 0; i < 4; ++i) {                        \
      int r = (w * 4 + i) * 8 + srow;                                      \
      const char* gp =                                                     \
          (const char*)(src + (size_t)(rbase + r) * K + k0) + sslot * 16;  \
      short* lp = dst + (w * 4 + i) * 512;                                 \
      __builtin_amdgcn_global_load_lds(                                    \
          (const __attribute__((address_space(1))) unsigned int*)gp,       \
          (__attribute__((address_space(3))) unsigned int*)lp, 16, 0, 0);  \
    }                                                                      \
  }

  for (int k0 = kbeg; k0 < kend; k0 += 64) {
    __syncthreads();
    STAGE4(Ash, Ah, row0)
    STAGE4(Asl, Al, row0)
    STAGE4(Bsh, Bh, col0)
    STAGE4(Bsl, Bl, col0)
    __syncthreads();
#pragma unroll
    for (int kc = 0; kc < 2; ++kc) {
      short8 ah[4], al[4], bh[4], bl[4];
#pragma unroll
      for (int mi = 0; mi < 4; ++mi) {
        int row = wm * 64 + mi * 16 + (l & 15);
        int slot = (kc * 4 + (l >> 4)) ^ (row & 7);
        ah[mi] = *(const short8*)&Ash[row * 64 + slot * 8];
        al[mi] = *(const short8*)&Asl[row * 64 + slot * 8];
      }
#pragma unroll
      for (int ni = 0; ni < 4; ++ni) {
        int row = wn * 64 + ni * 16 + (l & 15);
        int slot = (kc * 4 + (l >> 4)) ^ (row & 7);
        bh[ni] = *(const short8*)&Bsh[row * 64 + slot * 8];
        bl[ni] = *(const short8*)&Bsl[row * 64 + slot * 8];
      }
#pragma unroll
      for (int mi = 0; mi < 4; ++mi)
#pragma unroll
        for (int ni = 0; ni < 4; ++ni) {
          acc[mi][ni] = __builtin_amdgcn_mfma_f32_16x16x32_bf16(
              ah[mi], bh[ni], acc[mi][ni], 0, 0, 0);
          acc[mi][ni] = __builtin_amdgcn_mfma_f32_16x16x32_bf16(
              ah[mi], bl[ni], acc[mi][ni], 0, 0, 0);
          acc[mi][ni] = __builtin_amdgcn_mfma_f32_16x16x32_bf16(
              al[mi], bh[ni], acc[mi][ni], 0, 0, 0);
        }
    }
  }
#undef STAGE4

#pragma unroll
  for (int mi = 0; mi < 4; ++mi) {
#pragma unroll
    for (int ni = 0; ni < 4; ++ni) {
      int row = row0 + wm * 64 + mi * 16 + (l >> 4) * 4;
      int col = col0 + wn * 64 + ni * 16 + (l & 15);
      if (out32) {
        float bc = bias ? bias[col] : 0.f;
#pragma unroll
        for (int r = 0; r < 4; ++r)
          if (row + r < M)
            out32[(size_t)(row + r) * N + col] = acc[mi][ni][r] + bc;
      } else {
        float* Pz = P + (size_t)blockIdx.z * M * N;
#pragma unroll
        for (int r = 0; r < 4; ++r)
          if (row + r < M) Pz[(size_t)(row + r) * N + col] = acc[mi][ni][r];
      }
    }
  }
}

// ------ split-K reduce + bias + act + residual (+ LN); NSPLIT unrolled ----
template <int NSPLIT>
__global__ __launch_bounds__(256) void epilogue_kernel(
    const float* __restrict__ P, int M, int N, const float* __restrict__ bias,
    const float* __restrict__ res, float* __restrict__ out32,
    short* __restrict__ o16h, short* __restrict__ o16l, int act,
    const float* __restrict__ g, const float* __restrict__ bln,
    short* __restrict__ z16h, short* __restrict__ z16l) {
  __shared__ float sb[4];
  int r = blockIdx.x;
  float myval = 0.f;
  for (int c = threadIdx.x; c < N; c += 256) {
    const float* pp = P + (long long)r * N + c;
    float acc = 0.f;
#pragma unroll
    for (int s = 0; s < NSPLIT; ++s) acc += pp[(long long)s * M * N];
    acc += bias[c];
    if (act) acc = gelu_f(acc);
    if (res) acc += res[(long long)r * N + c];
    if (out32) out32[(long long)r * N + c] = acc;
    if (o16h) {
      short h, L;
      split2(acc, h, L);
      o16h[(long long)r * N + swz(c, r)] = h;
      o16l[(long long)r * N + swz(c, r)] = L;
    }
    myval = acc;
  }
  if (z16h) {  // N==256 only
    float mean = block_sum_256(myval, sb) * (1.f / 256.f);
    float dv = myval - mean;
    float var = block_sum_256(dv * dv, sb) * (1.f / 256.f);
    float z = dv * rsqrtf(var + 1e-5f) * g[threadIdx.x] + bln[threadIdx.x];
    short h, L;
    split2(z, h, L);
    z16h[r * 256 + swz((int)threadIdx.x, r)] = h;
    z16l[r * 256 + swz((int)threadIdx.x, r)] = L;
  }
}

// ------- attention (fp32 qkv in, hi/lo bf16 out), 17 q-rows per block -----
#define AROWS 17
__global__ __launch_bounds__(256) void attn_kernel(const float* __restrict__ qkv,
                                                   short* __restrict__ Oh,
                                                   short* __restrict__ Ol) {
  __shared__ float qs[AROWS + 1][256];
  __shared__ float Ks[68][68];
  __shared__ float ps[AROWS][66];
  const int tid = threadIdx.x;
  const int s0 = blockIdx.x * AROWS;
  const int bh = blockIdx.y;
  const int b = bh >> 4, h = bh & 15;
  const long long base = (long long)(b * 65) * 12288 + h * 768;

#pragma unroll
  for (int i = 0; i < AROWS; ++i) {
    int s = s0 + i;
    qs[i][tid] = (s < 65) ? qkv[base + (long long)s * 12288 + tid] : 0.f;
  }

  const int up = tid / 17, tg = tid % 17;
  const int i0 = up * 2, t0 = tg * 4;
  const bool uval = (tid < 153);
  float acc[2][4] = {};
  for (int dc = 0; dc < 256; dc += 64) {
    __syncthreads();
    for (int idx = tid; idx < 65 * 64; idx += 256) {
      int t = idx >> 6, dd = idx & 63;
      Ks[t][dd] = qkv[base + (long long)t * 12288 + 256 + dc + dd];
    }
    __syncthreads();
    if (uval) {
#pragma unroll
      for (int d4 = 0; d4 < 64; d4 += 4) {
        float4 qa = *(const float4*)&qs[i0][dc + d4];
        float4 qb = *(const float4*)&qs[i0 + 1][dc + d4];
#pragma unroll
        for (int c = 0; c < 4; ++c) {
          float4 kv = *(const float4*)&Ks[t0 + c][d4];
          acc[0][c] += qa.x * kv.x + qa.y * kv.y + qa.z * kv.z + qa.w * kv.w;
          acc[1][c] += qb.x * kv.x + qb.y * kv.y + qb.z * kv.z + qb.w * kv.w;
        }
      }
    }
  }
  if (uval) {
#pragma unroll
    for (int ii = 0; ii < 2; ++ii) {
      int i = i0 + ii;
      if (i < AROWS && (s0 + i) < 65) {
#pragma unroll
        for (int c = 0; c < 4; ++c) {
          int t = t0 + c;
          if (t < 65) ps[i][t] = acc[ii][c] * 0.25f;
        }
      }
    }
  }
  __syncthreads();

  if (tid < AROWS && (s0 + tid) < 65) {
    float* row = ps[tid];
    float m = row[0];
    for (int t = 1; t < 65; ++t) m = fmaxf(m, row[t]);
    float sum = 0.f;
    for (int t = 0; t < 65; ++t) {
      float e = expf(row[t] - m);
      row[t] = e;
      sum += e;
    }
    float inv = 1.f / sum;
    for (int t = 0; t < 65; ++t) row[t] *= inv;
  }
  __syncthreads();

  float oacc[AROWS];
#pragma unroll
  for (int i = 0; i < AROWS; ++i) oacc[i] = 0.f;
  const float* vp = qkv + base + 512 + tid;
  for (int t = 0; t < 65; ++t) {
    float vtd = vp[(long long)t * 12288];
#pragma unroll
    for (int i = 0; i < AROWS; ++i) oacc[i] += ps[i][t] * vtd;
  }
#pragma unroll
  for (int i = 0; i < AROWS; ++i) {
    int s = s0 + i;
    if (s < 65) {
      int row = b * 65 + s;
      int col = h * 256 + ((tid & ~63) | ((tid & 63) ^ ((row & 7) << 3)));
      short hh, LL;
      split2(oacc[i], hh, LL);
      Oh[(long long)row * 4096 + col] = hh;
      Ol[(long long)row * 4096 + col] = LL;
    }
  }
}

// ---------------- head GEMMs (fp32, tiny) ----------------
template <int KS>
__global__ __launch_bounds__(256) void head_gemm2(
    const float* __restrict__ A, int lda, const float* __restrict__ B,
    const float* __restrict__ bias, float* __restrict__ C, int N, int K,
    int act) {
  constexpr int COLS = 256 / KS;
  __shared__ float red[KS][COLS];
  const int lane = threadIdx.x % COLS;
  const int ks = threadIdx.x / COLS;
  const int c = blockIdx.x * COLS + lane;
  const int r = blockIdx.y;
  const float* a = A + (long long)r * lda;
  float acc = 0.f;
  const int kc = K / KS;
  if (c < N) {
    const float* ap = a + ks * kc;
    const float* bp = B + (long long)(ks * kc) * N + c;
#pragma unroll 8
    for (int k = 0; k < kc; ++k) acc += ap[k] * bp[(long long)k * N];
  }
  red[ks][lane] = acc;
  __syncthreads();
  if (ks == 0 && c < N) {
    float v = bias[c];
#pragma unroll
    for (int s = 0; s < KS; ++s) v += red[s][lane];
    if (act) v = gelu_f(v);
    C[(long long)r * N + c] = v;
  }
}

extern "C" void kernel_launch(void* const* d_in, const int* in_sizes, int n_in,
                              void* d_out, int out_size, void* d_ws,
                              size_t ws_size, hipStream_t stream) {
  const float* x = (const float*)d_in[0];
  const float* conv_w = (const float*)d_in[1];
  const float* conv_b = (const float*)d_in[2];
  const float* cls = (const float*)d_in[3];
  const float* pos = (const float*)d_in[4];
  const float* Wqkv = (const float*)d_in[5];
  const float* bqkv = (const float*)d_in[6];
  const float* Wo = (const float*)d_in[7];
  const float* bo = (const float*)d_in[8];
  const float* ln1g = (const float*)d_in[9];
  const float* ln1b = (const float*)d_in[10];
  const float* ln2g = (const float*)d_in[11];
  const float* ln2b = (const float*)d_in[12];
  const float* Wm1 = (const float*)d_in[13];
  const float* bm1 = (const float*)d_in[14];
  const float* Wm2 = (const float*)d_in[15];
  const float* bm2 = (const float*)d_in[16];
  const float* Wh1 = (const float*)d_in[17];
  const float* bh1 = (const float*)d_in[18];
  const float* Wh2 = (const float*)d_in[19];
  const float* bh2 = (const float*)d_in[20];
  const float* Wh3 = (const float*)d_in[21];
  const float* bh3 = (const float*)d_in[22];
  float* out = (float*)d_out;

  // ---- workspace map (float units; identical to round-5 proven map) ----
  float* ws = (float*)d_ws;
  float* tok = ws;
  float* y1 = ws + 163840;
  float* Pb = ws + 327680;
  float* qkvf = ws + 2457600;
  short* zh = (short*)(ws + 8847360);
  short* zl = (short*)(ws + 8929280);
  short* Oh = (short*)(ws + 9011200);
  short* Ol = (short*)(ws + 10321920);
  short* h1h = (short*)(ws + 11632640);
  short* h1l = (short*)(ws + 11960320);
  float* hh1 = ws + 12288000;
  float* hh2 = ws + 12296192;
  short* Wqh = (short*)(ws + 12298240);
  short* Wql = (short*)(ws + 50046976);
  short* Woh = (short*)(ws + 87795712);
  short* Wol_ = (short*)(ws + 100378624);
  short* W1h = (short*)(ws + 112961536);
  short* W1l = (short*)(ws + 116107264);
  short* W2h = (short*)(ws + 119252992);
  short* W2l = (short*)(ws + 122398720);

  const int M = 520;

  // one prep dispatch: embed+LN1 (520 blocks) + all weight converts
  PrepArgs p;
  p.x = x; p.cw = conv_w; p.cb = conv_b; p.cls = cls; p.pos = pos;
  p.ln1g = ln1g; p.ln1b = ln1b;
  p.tok = tok; p.zh = zh; p.zl = zl;
  p.Wqkv = Wqkv; p.Wo = Wo; p.Wm1 = Wm1; p.Wm2 = Wm2;
  p.Wqh = Wqh; p.Wql = Wql; p.Woh = Woh; p.Wol = Wol_;
  p.W1h = W1h; p.W1l = W1l; p.W2h = W2h; p.W2l = W2l;
  prep_kernel<<<520 + 24 * 576, 256, 0, stream>>>(p);

  for (int l = 0; l < 24; ++l) {
    const short* Wqhl = Wqh + (long long)l * 3145728;
    const short* Wqll = Wql + (long long)l * 3145728;
    const short* Wohl = Woh + (long long)l * 1048576;
    const short* Woll = Wol_ + (long long)l * 1048576;
    const short* W1hl = W1h + (long long)l * 262144;
    const short* W1ll = W1l + (long long)l * 262144;
    const short* W2hl = W2h + (long long)l * 262144;
    const short* W2ll = W2l + (long long)l * 262144;
    const float* bq = bqkv + l * 12288;
    const float* bol = bo + l * 256;
    const float* b1 = bm1 + l * 1024;
    const float* b2 = bm2 + l * 256;

    // QKV: z @ Wq -> qkvf fp32 (+bias)
    gemm_x3<<<dim3(96, 5, 1), 256, 0, stream>>>(zh, zl, Wqhl, Wqll, M, 12288,
                                                256, 256, bq, qkvf, nullptr);

    attn_kernel<<<dim3(4, 128), 256, 0, stream>>>(qkvf, Oh, Ol);

    // Wo: O(520x4096) @ Wo'(256x4096), split-K 16 -> Pb
    gemm_x3<<<dim3(2, 5, 16), 256, 0, stream>>>(Oh, Ol, Wohl, Woll, M, 256,
                                                4096, 256, nullptr, nullptr,
                                                Pb);
    epilogue_kernel<16><<<520, 256, 0, stream>>>(
        Pb, M, 256, bol, tok, y1, nullptr, nullptr, 0, ln2g + l * 256,
        ln2b + l * 256, zh, zl);

    // MLP1: z @ Wm1'(1024x256), split-K 4, gelu -> h1 hi/lo
    gemm_x3<<<dim3(8, 5, 4), 256, 0, stream>>>(zh, zl, W1hl, W1ll, M, 1024,
                                               256, 64, nullptr, nullptr, Pb);
    epilogue_kernel<4><<<520, 256, 0, stream>>>(Pb, M, 1024, b1, nullptr,
                                                nullptr, h1h, h1l, 1, nullptr,
                                                nullptr, nullptr, nullptr);

    // MLP2: h1 @ Wm2'(256x1024), split-K 16 -> Pb
    gemm_x3<<<dim3(2, 5, 16), 256, 0, stream>>>(h1h, h1l, W2hl, W2ll, M, 256,
                                                1024, 64, nullptr, nullptr,
                                                Pb);
    const float* ng = (l < 23) ? ln1g + (l + 1) * 256 : nullptr;
    const float* nb = (l < 23) ? ln1b + (l + 1) * 256 : nullptr;
    short* nzh = (l < 23) ? zh : nullptr;
    short* nzl = (l < 23) ? zl : nullptr;
    epilogue_kernel<16><<<520, 256, 0, stream>>>(Pb, M, 256, b2, y1, tok,
                                                 nullptr, nullptr, 1, ng, nb,
                                                 nzh, nzl);
  }

  head_gemm2<4><<<dim3(16, 8), 256, 0, stream>>>(tok, 16640, Wh1, bh1, hh1,
                                                 1024, 256, 1);
  head_gemm2<8><<<dim3(8, 8), 256, 0, stream>>>(hh1, 1024, Wh2, bh2, hh2, 256,
                                                1024, 1);
  head_gemm2<4><<<dim3(16, 8), 256, 0, stream>>>(hh2, 256, Wh3, bh3, out, 1000,
                                                 256, 0);
}